// Round 7
// baseline (351.869 us; speedup 1.0000x reference)
//
#include <hip/hip_runtime.h>

typedef _Float16 f16;
typedef _Float16 f16x8 __attribute__((ext_vector_type(8)));
typedef _Float16 f16x4 __attribute__((ext_vector_type(4)));
typedef float f32x4 __attribute__((ext_vector_type(4)));

#define MFMA16(a, b, c) __builtin_amdgcn_mfma_f32_16x16x32_f16(a, b, c, 0, 0, 0)
#define MFMA16K16(a, b, c) __builtin_amdgcn_mfma_f32_16x16x16f16(a, b, c, 0, 0, 0)

// =====================================================================
// k_mt: M_h = Wq_h^T Wk_h, stored K-blocked:
//   MT[((h*nkk + (e>>5))*H + f)*32 + (e&31)] = sum_d Wq[h*H+d][e]*Wk[h*H+d][f]
// =====================================================================
__global__ __launch_bounds__(256) void k_mt(const float* __restrict__ Wq,
                                            const float* __restrict__ Wk,
                                            f16* __restrict__ MT, int H) {
    const int h = blockIdx.x;
    const int ntile = H >> 6;
    const int nkk = H >> 5;
    const int frow = (blockIdx.y / ntile) * 64;
    const int ecol = (blockIdx.y % ntile) * 64;
    const int t = threadIdx.x;
    const int lane = t & 63;
    const int w = t >> 6;
    const int wr = w >> 1, wc = w & 1;

    __shared__ __align__(16) f16 As[64][40];
    __shared__ __align__(16) f16 Ks[64][40];

    f32x4 acc[2][2] = {};
    const int d = t >> 3;
    const int e8 = (t & 7) * 8;

    for (int kk = 0; kk < nkk; ++kk) {
        const float* gq = Wq + (size_t)(h * H + kk * 32 + d) * H + ecol + e8;
        const float* gk = Wk + (size_t)(h * H + kk * 32 + d) * H + frow + e8;
        float q[8], k[8];
#pragma unroll
        for (int i = 0; i < 8; ++i) { q[i] = gq[i]; k[i] = gk[i]; }
        __syncthreads();
#pragma unroll
        for (int i = 0; i < 8; ++i) { As[e8 + i][d] = (f16)q[i]; Ks[e8 + i][d] = (f16)k[i]; }
        __syncthreads();
        f16x8 a[2], b[2];
#pragma unroll
        for (int rt = 0; rt < 2; ++rt)
            a[rt] = *(const f16x8*)&Ks[wr * 32 + rt * 16 + (lane & 15)][(lane >> 4) * 8];
#pragma unroll
        for (int nt = 0; nt < 2; ++nt)
            b[nt] = *(const f16x8*)&As[wc * 32 + nt * 16 + (lane & 15)][(lane >> 4) * 8];
#pragma unroll
        for (int rt = 0; rt < 2; ++rt)
#pragma unroll
            for (int nt = 0; nt < 2; ++nt)
                acc[rt][nt] = MFMA16(a[rt], b[nt], acc[rt][nt]);
    }
#pragma unroll
    for (int rt = 0; rt < 2; ++rt)
#pragma unroll
        for (int nt = 0; nt < 2; ++nt)
#pragma unroll
            for (int j = 0; j < 4; ++j) {
                int f = frow + wr * 32 + rt * 16 + (lane >> 4) * 4 + j;
                int e = ecol + wc * 32 + nt * 16 + (lane & 15);
                MT[(((size_t)h * nkk + (e >> 5)) * H + f) * 32 + (e & 31)] = (f16)acc[rt][nt][j];
            }
}

// =====================================================================
// k_lin: out[r][j] = sum_d in[r][d]*W[j][d] + b[j], J=256, 4 rows/block.
// =====================================================================
__global__ __launch_bounds__(256) void k_lin(const float* __restrict__ in,
                                             const float* __restrict__ W,
                                             const float* __restrict__ bias,
                                             float* __restrict__ out, int K) {
    const int t = threadIdx.x;
    const int r0 = blockIdx.x * 4;
    __shared__ float ins[4][384];
    __shared__ float Ws[256][33];
#pragma unroll
    for (int r = 0; r < 4; ++r)
        for (int off = t; off < K; off += 256)
            ins[r][off] = in[(size_t)(r0 + r) * K + off];
    float acc[4] = {};
    for (int d0 = 0; d0 < K; d0 += 32) {
        __syncthreads();
        for (int i = t; i < 256 * 32; i += 256) {
            int j = i >> 5, dd = i & 31;
            Ws[j][dd] = W[(size_t)j * K + d0 + dd];
        }
        __syncthreads();
#pragma unroll 8
        for (int dd = 0; dd < 32; ++dd) {
            float wv = Ws[t][dd];
#pragma unroll
            for (int r = 0; r < 4; ++r) acc[r] += wv * ins[r][d0 + dd];
        }
    }
    float bv = bias[t];
#pragma unroll
    for (int r = 0; r < 4; ++r) out[(size_t)(r0 + r) * 256 + t] = acc[r] + bv;
}

// =====================================================================
// k_small_int: 4 pos-groups/block (16 X-rows) -> 1024 blocks, 4 blk/CU.
// grid (64, 16), block 256, static LDS ~17 KB.
// =====================================================================
__global__ __launch_bounds__(256) void k_small_int(const float* __restrict__ X,
                                                   const f16* __restrict__ MT,
                                                   float* __restrict__ wpart) {
    const int t = threadIdx.x;
    const int lane = t & 63;
    const int w = t >> 6;
    const int g = lane >> 4;
    const int l15 = lane & 15;
    const int pos0 = blockIdx.x * 4;
    const int h = blockIdx.y;

    __shared__ __align__(16) f16 Xs[16][264];
    __shared__ __align__(16) f16 Ts[16][264];

    {
        int row = t >> 4, d0 = (t & 15) * 16;
        int s = row & 3, p = row >> 2;
        const float* gx = X + (size_t)(s * 256 + pos0 + p) * 256 + d0;
#pragma unroll
        for (int i = 0; i < 16; i += 8) {
            float4 v0 = *(const float4*)(gx + i);
            float4 v1 = *(const float4*)(gx + i + 4);
            f16x8 o;
            o[0] = (f16)v0.x; o[1] = (f16)v0.y; o[2] = (f16)v0.z; o[3] = (f16)v0.w;
            o[4] = (f16)v1.x; o[5] = (f16)v1.y; o[6] = (f16)v1.z; o[7] = (f16)v1.w;
            *(f16x8*)&Xs[row][d0 + i] = o;
        }
    }
    __syncthreads();

    const f16* mh = MT + (size_t)h * 8 * 256 * 32;
    const int fb = w * 64 + l15;
    f32x4 acc[4] = {};
    f16x8 bq[4], bn[4];
#pragma unroll
    for (int nt = 0; nt < 4; ++nt)
        bq[nt] = *(const f16x8*)(mh + (size_t)(fb + nt * 16) * 32 + g * 8);
#pragma unroll
    for (int kk = 0; kk < 8; ++kk) {
        if (kk < 7) {
#pragma unroll
            for (int nt = 0; nt < 4; ++nt)
                bn[nt] = *(const f16x8*)(mh + ((size_t)(kk + 1) * 256 + fb + nt * 16) * 32 + g * 8);
        }
        f16x8 a = *(const f16x8*)&Xs[l15][kk * 32 + g * 8];
#pragma unroll
        for (int nt = 0; nt < 4; ++nt) acc[nt] = MFMA16(a, bq[nt], acc[nt]);
#pragma unroll
        for (int nt = 0; nt < 4; ++nt) bq[nt] = bn[nt];
    }
#pragma unroll
    for (int nt = 0; nt < 4; ++nt)
#pragma unroll
        for (int j = 0; j < 4; ++j)
            Ts[g * 4 + j][w * 64 + nt * 16 + l15] = (f16)acc[nt][j];
    __syncthreads();

    f32x4 sacc = {};
#pragma unroll
    for (int ks = 0; ks < 8; ++ks) {
        f16x8 a = *(const f16x8*)&Ts[l15][ks * 32 + g * 8];
        f16x8 b = *(const f16x8*)&Xs[l15][ks * 32 + g * 8];
        sacc = MFMA16(a, b, sacc);
    }
    if (w == 0 && (l15 >> 2) == g) {
        const float scale = 1.0f / 16.0f; // 1/sqrt(256)
        float add = 0.f;
#pragma unroll
        for (int j = 0; j < 4; ++j) {
            float v = sacc[j] * scale;
            float m = v;
            m = fmaxf(m, __shfl_xor(m, 1));
            m = fmaxf(m, __shfl_xor(m, 2));
            float e = expf(v - m);
            float s2 = e;
            s2 += __shfl_xor(s2, 1);
            s2 += __shfl_xor(s2, 2);
            add += e / s2;
        }
        int pg = pos0 + g;
        wpart[((size_t)h * 256 + pg) * 4 + (l15 & 3)] = add;
    }
}

// =====================================================================
// k_small_fin: sum 16 head-partials -> /64 -> softmax(4) -> pool states.
// =====================================================================
__global__ __launch_bounds__(256) void k_small_fin(const float* __restrict__ wpart,
                                                   const float* __restrict__ X,
                                                   float* __restrict__ out_int,
                                                   float* __restrict__ out_w) {
    const int pos = blockIdx.x, t = threadIdx.x;
    __shared__ float red[64];
    __shared__ float ws[4];
    if (t < 64) red[t] = wpart[((size_t)(t >> 2) * 256 + pos) * 4 + (t & 3)];
    __syncthreads();
    if (t == 0) {
        float v[4];
#pragma unroll
        for (int s = 0; s < 4; ++s) {
            float x = 0.f;
            for (int hh = 0; hh < 16; ++hh) x += red[hh * 4 + s];
            v[s] = x * (1.0f / 64.0f);
        }
        float m = fmaxf(fmaxf(v[0], v[1]), fmaxf(v[2], v[3]));
        float sum = 0.f;
#pragma unroll
        for (int s = 0; s < 4; ++s) { v[s] = expf(v[s] - m); sum += v[s]; }
#pragma unroll
        for (int s = 0; s < 4; ++s) ws[s] = v[s] / sum;
    }
    __syncthreads();
    if (t < 4) out_w[pos * 4 + t] = ws[t];
    float v = 0.f;
#pragma unroll
    for (int s = 0; s < 4; ++s) v += ws[s] * X[(size_t)(s * 256 + pos) * 256 + t];
    out_int[(size_t)pos * 256 + t] = v;
}

// =====================================================================
// k_ce_int v7: 8 waves x 48 M-cols, 4 waves/SIMD (VGPR<=128 target).
// Tt = M^T X (lane=token); phase2 B-frag == acc layout (K16 MFMA).
// S-partial merge: XOR-pair tree (b: w^4 two sub-rounds / it: w^2 / lt: w^1),
// softmax max/den combined with it-partner via 512B mini-exchange.
// Xs: 64x768B swizzled @ [0,49152). EX: 16KB @ 49152. LDS 65536 -> 2 blk/CU.
// acc_out: [16][1024][2][32]. grid 512, block 512.
// =====================================================================
#define EX_OFF 49152

__global__ __launch_bounds__(512, 2) void k_ce_int(const float* __restrict__ Xg32,
                                                   const f16* __restrict__ MT,
                                                   float* __restrict__ acc_out) {
    const int t = threadIdx.x;
    const int lane = t & 63;
    const int w = t >> 6;       // 0..7
    const int g = lane >> 4;
    const int l15 = lane & 15;
    const int bg = blockIdx.x;

    extern __shared__ __align__(16) char smem[];
    char* EX = smem + EX_OFF;

    // ---- stage X (64 x 384), f32 -> f16, source-swizzled, linear LDS ----
    {
        const float* xg = Xg32 + (size_t)bg * 64 * 384;
#pragma unroll
        for (int p = 0; p < 6; ++p) {
            int idx = p * 512 + t;
            int row = idx / 48, s = idx - row * 48;
            int c = s ^ (row & 7);
            const float* src = xg + row * 384 + c * 8;
            float4 v0 = *(const float4*)src;
            float4 v1 = *(const float4*)(src + 4);
            f16x8 o;
            o[0] = (f16)v0.x; o[1] = (f16)v0.y; o[2] = (f16)v0.z; o[3] = (f16)v0.w;
            o[4] = (f16)v1.x; o[5] = (f16)v1.y; o[6] = (f16)v1.z; o[7] = (f16)v1.w;
            *(f16x8*)(smem + idx * 16) = o;
        }
    }
    __syncthreads();

    const f16* mall = MT;            // [16*12 steps][384][32]
    const int frow = w * 48 + l15;

    // depth-1 ping-pong M prefetch
    f16x8 A[2][3];
#pragma unroll
    for (int ft = 0; ft < 3; ++ft)
        A[0][ft] = *(const f16x8*)(mall + (size_t)(frow + ft * 16) * 32 + g * 8);

    for (int hi = 0; hi < 16; ++hi) {
        // ---- phase 1: Tt = M_h^T @ X; wave owns 48 e'-rows, 64 tokens ----
        f32x4 acc[3][4] = {};
#pragma unroll
        for (int kk = 0; kk < 12; ++kk) {
            {
                int step = hi * 12 + kk + 1;
                int ns = step < 192 ? step : 191;
#pragma unroll
                for (int ft = 0; ft < 3; ++ft)
                    A[(kk + 1) & 1][ft] =
                        *(const f16x8*)(mall + (size_t)ns * 12288 + (size_t)(frow + ft * 16) * 32 + g * 8);
            }
            const int xaddr = l15 * 768 + (((kk * 4 + g) ^ (l15 & 7)) << 4);
            f16x8 xb[4];
#pragma unroll
            for (int mt = 0; mt < 4; ++mt)
                xb[mt] = *(const f16x8*)(smem + xaddr + mt * 12288);
            __builtin_amdgcn_s_setprio(1);
#pragma unroll
            for (int ft = 0; ft < 3; ++ft)
#pragma unroll
                for (int mt = 0; mt < 4; ++mt)
                    acc[ft][mt] = MFMA16(A[kk & 1][ft], xb[mt], acc[ft][mt]);
            __builtin_amdgcn_s_setprio(0);
        }

        // ---- cast Tt acc -> f16 B-frags (layout == K16 B-frag) ----
        f16x4 bf[3][4];
#pragma unroll
        for (int ft = 0; ft < 3; ++ft)
#pragma unroll
            for (int mt = 0; mt < 4; ++mt) {
                f32x4 v = acc[ft][mt];
                f16x4 o;
                o[0] = (f16)v[0]; o[1] = (f16)v[1]; o[2] = (f16)v[2]; o[3] = (f16)v[3];
                bf[ft][mt] = o;
            }

        // ---- phase 2: S partials over wave's 48 e' (reg-only) ----
        f32x4 s2[2][2][2] = {};  // [b][it][lt]
#pragma unroll
        for (int b = 0; b < 2; ++b)
#pragma unroll
            for (int ks = 0; ks < 3; ++ks)
#pragma unroll
                for (int it = 0; it < 2; ++it) {
                    int ch = 6 * w + 2 * ks + (g >> 1);
                    int av_addr = b * 24576 + it * 12288 + l15 * 768 +
                                  ((ch ^ (l15 & 7)) << 4) + 8 * (g & 1);
                    f16x4 av = *(const f16x4*)(smem + av_addr);
#pragma unroll
                    for (int lt = 0; lt < 2; ++lt)
                        s2[b][it][lt] = MFMA16K16(av, bf[ks][b * 2 + lt], s2[b][it][lt]);
                }

        // ---- r1: b-split (partner w^4), two sub-rounds, 16KB buffer ----
        f32x4 p00, p01, p10, p11;
        if (w >= 4) {
            char* dst = EX + (w - 4) * 4096 + lane * 16;
            *(f32x4*)(dst) = s2[0][0][0];
            *(f32x4*)(dst + 1024) = s2[0][0][1];
            *(f32x4*)(dst + 2048) = s2[0][1][0];
            *(f32x4*)(dst + 3072) = s2[0][1][1];
        }
        __syncthreads();
        if (w < 4) {
            const char* pb = EX + w * 4096 + lane * 16;
            p00 = s2[0][0][0] + *(const f32x4*)(pb);
            p01 = s2[0][0][1] + *(const f32x4*)(pb + 1024);
            p10 = s2[0][1][0] + *(const f32x4*)(pb + 2048);
            p11 = s2[0][1][1] + *(const f32x4*)(pb + 3072);
            char* dst = EX + w * 4096 + lane * 16;
            *(f32x4*)(dst) = s2[1][0][0];
            *(f32x4*)(dst + 1024) = s2[1][0][1];
            *(f32x4*)(dst + 2048) = s2[1][1][0];
            *(f32x4*)(dst + 3072) = s2[1][1][1];
        }
        __syncthreads();
        if (w >= 4) {
            const char* pb = EX + (w - 4) * 4096 + lane * 16;
            p00 = s2[1][0][0] + *(const f32x4*)(pb);
            p01 = s2[1][0][1] + *(const f32x4*)(pb + 1024);
            p10 = s2[1][1][0] + *(const f32x4*)(pb + 2048);
            p11 = s2[1][1][1] + *(const f32x4*)(pb + 3072);
        }
        __syncthreads();

        // ---- r2: it-split (partner w^2) ----
        {
            char* dst = EX + w * 2048 + lane * 16;
            if ((w & 2) == 0) { *(f32x4*)dst = p10; *(f32x4*)(dst + 1024) = p11; }
            else              { *(f32x4*)dst = p00; *(f32x4*)(dst + 1024) = p01; }
        }
        __syncthreads();
        f32x4 q0, q1;
        {
            const char* pb = EX + (w ^ 2) * 2048 + lane * 16;
            if ((w & 2) == 0) { q0 = p00 + *(const f32x4*)pb; q1 = p01 + *(const f32x4*)(pb + 1024); }
            else              { q0 = p10 + *(const f32x4*)pb; q1 = p11 + *(const f32x4*)(pb + 1024); }
        }
        __syncthreads();

        // ---- r3: lt-split (partner w^1) ----
        {
            char* dst = EX + w * 1024 + lane * 16;
            if ((w & 1) == 0) *(f32x4*)dst = q1;
            else              *(f32x4*)dst = q0;
        }
        __syncthreads();
        f32x4 fin;
        {
            const char* pb = EX + (w ^ 1) * 1024 + lane * 16;
            if ((w & 1) == 0) fin = q0 + *(const f32x4*)pb;
            else              fin = q1 + *(const f32x4*)pb;
        }
        __syncthreads();

        // ---- softmax over m (32 rows), cols olt*16+l15; it-partner = w^2 ----
        {
            const float scale = 0.051031036307982884f; // 1/sqrt(384)
            float v0 = fin[0] * scale, v1 = fin[1] * scale;
            float v2 = fin[2] * scale, v3 = fin[3] * scale;
            float lm = fmaxf(fmaxf(v0, v1), fmaxf(v2, v3));
            lm = fmaxf(lm, __shfl_xor(lm, 16));
            lm = fmaxf(lm, __shfl_xor(lm, 32));
            if (lane < 16) *(float*)(EX + w * 64 + lane * 4) = lm;
            __syncthreads();
            float m = fmaxf(lm, *(const float*)(EX + (w ^ 2) * 64 + l15 * 4));
            float e0 = expf(v0 - m), e1 = expf(v1 - m);
            float e2 = expf(v2 - m), e3 = expf(v3 - m);
            float ls = e0 + e1 + e2 + e3;
            ls += __shfl_xor(ls, 16);
            ls += __shfl_xor(ls, 32);
            if (lane < 16) *(float*)(EX + 512 + w * 64 + lane * 4) = ls;
            __syncthreads();
            float den = ls + *(const float*)(EX + 512 + (w ^ 2) * 64 + l15 * 4);
            float inv = 1.f / den;
            float r0 = e0 * inv, r1 = e1 * inv, r2 = e2 * inv, r3 = e3 * inv;
#pragma unroll
            for (int d = 1; d < 16; d <<= 1) {
                r0 += __shfl_xor(r0, d);
                r1 += __shfl_xor(r1, d);
                r2 += __shfl_xor(r2, d);
                r3 += __shfl_xor(r3, d);
            }
            if (l15 == 0) {
                const int ob = w >> 2, oit = (w >> 1) & 1, olt = w & 1;
                float* o = acc_out + (((size_t)hi * 1024 + bg * 2 + ob) * 2 + olt) * 32 +
                           oit * 16 + g * 4;
                o[0] = r0; o[1] = r1; o[2] = r2; o[3] = r3;
            }
        }
        __syncthreads();  // protect EX for next head
    }
}

// =====================================================================
// k_ce_pool: w = softmax(sum_{h,lt} accp / 512); pooled = sum_m w[m]*exv
// accp: [16][1024][2][32]
// =====================================================================
__global__ __launch_bounds__(128) void k_ce_pool(const float* __restrict__ accp,
                                                 const float* __restrict__ exv,
                                                 float* __restrict__ pooled) {
    const int b = blockIdx.x;
    const int t = threadIdx.x;
    __shared__ float wm[32];
    __shared__ float ww[32];
    if (t < 32) {
        float s = 0.f;
#pragma unroll
        for (int h = 0; h < 16; ++h) {
            s += accp[(((size_t)h * 1024 + b) * 2 + 0) * 32 + t];
            s += accp[(((size_t)h * 1024 + b) * 2 + 1) * 32 + t];
        }
        wm[t] = s * (1.0f / 512.0f);
    }
    __syncthreads();
    if (t == 0) {
        float m = wm[0];
        for (int i = 1; i < 32; ++i) m = fmaxf(m, wm[i]);
        float s = 0.f;
        for (int i = 0; i < 32; ++i) { float e = expf(wm[i] - m); ww[i] = e; s += e; }
        float inv = 1.f / s;
        for (int i = 0; i < 32; ++i) ww[i] *= inv;
    }
    __syncthreads();
    for (int d = t; d < 384; d += 128) {
        float v = 0.f;
#pragma unroll
        for (int m = 0; m < 32; ++m) v += ww[m] * exv[((size_t)b * 32 + m) * 384 + d];
        pooled[(size_t)b * 384 + d] = v;
    }
}

// =====================================================================
extern "C" void kernel_launch(void* const* d_in, const int* in_sizes, int n_in,
                              void* d_out, int out_size, void* d_ws, size_t ws_size,
                              hipStream_t stream) {
    const float* h_V    = (const float*)d_in[0];
    const float* h_EXV  = (const float*)d_in[1];
    const float* W_hV   = (const float*)d_in[2];
    const float* b_hV   = (const float*)d_in[3];
    const float* Wq_hv  = (const float*)d_in[4];
    const float* Wk_hv  = (const float*)d_in[5];
    const float* Wq_ce  = (const float*)d_in[6];
    const float* Wk_ce  = (const float*)d_in[7];
    const float* W_ce   = (const float*)d_in[8];
    const float* b_ce   = (const float*)d_in[9];
    const float* Wq_sce = (const float*)d_in[10];
    const float* Wk_sce = (const float*)d_in[11];
    float* out = (float*)d_out;

    char* ws = (char*)d_ws;
    f16*   mt_hv  = (f16*)(ws + 0);           //  2,097,152
    f16*   mt_sce = (f16*)(ws + 2097152);     //  2,097,152
    f16*   mt_ce  = (f16*)(ws + 4194304);     //  4,718,592
    float* hv     = (float*)(ws + 8912896);   //  1,048,576
    float* ce     = (float*)(ws + 9961472);   //  1,048,576
    float* accp   = (float*)(ws + 11010048);  //  4,194,304
    float* pooled = (float*)(ws + 15204352);  //  1,572,864  (total ~16.8 MB)
    float* wpart  = accp;                     // alias: lifetimes ordered

    k_mt<<<dim3(16, 16), 256, 0, stream>>>(Wq_hv, Wk_hv, mt_hv, 256);
    k_mt<<<dim3(16, 36), 256, 0, stream>>>(Wq_ce, Wk_ce, mt_ce, 384);
    k_mt<<<dim3(16, 16), 256, 0, stream>>>(Wq_sce, Wk_sce, mt_sce, 256);
    k_lin<<<256, 256, 0, stream>>>(h_V, W_hV, b_hV, hv, 128);
    k_small_int<<<dim3(64, 16), 256, 0, stream>>>(hv, mt_hv, wpart);
    k_small_fin<<<256, 256, 0, stream>>>(wpart, hv, out + 0, out + 65536);
    k_ce_int<<<dim3(512), 512, 65536, stream>>>(h_EXV, mt_ce, accp);
    k_ce_pool<<<1024, 128, 0, stream>>>(accp, h_EXV, pooled);
    k_lin<<<256, 256, 0, stream>>>(pooled, W_ce, b_ce, ce, 384);
    k_small_int<<<dim3(64, 16), 256, 0, stream>>>(ce, mt_sce, wpart);
    k_small_fin<<<256, 256, 0, stream>>>(wpart, ce, out + 66560, out + 132096);
}

// Round 8
// 318.745 us; speedup vs baseline: 1.1039x; 1.1039x over previous
//
#include <hip/hip_runtime.h>

typedef _Float16 f16;
typedef _Float16 f16x8 __attribute__((ext_vector_type(8)));
typedef _Float16 f16x4 __attribute__((ext_vector_type(4)));
typedef float f32x4 __attribute__((ext_vector_type(4)));

#define MFMA16(a, b, c) __builtin_amdgcn_mfma_f32_16x16x32_f16(a, b, c, 0, 0, 0)
#define MFMA16K16(a, b, c) __builtin_amdgcn_mfma_f32_16x16x16f16(a, b, c, 0, 0, 0)

// =====================================================================
// k_mt: M_h = Wq_h^T Wk_h, stored K-blocked:
//   MT[((h*nkk + (e>>5))*H + f)*32 + (e&31)] = sum_d Wq[h*H+d][e]*Wk[h*H+d][f]
// =====================================================================
__global__ __launch_bounds__(256) void k_mt(const float* __restrict__ Wq,
                                            const float* __restrict__ Wk,
                                            f16* __restrict__ MT, int H) {
    const int h = blockIdx.x;
    const int ntile = H >> 6;
    const int nkk = H >> 5;
    const int frow = (blockIdx.y / ntile) * 64;
    const int ecol = (blockIdx.y % ntile) * 64;
    const int t = threadIdx.x;
    const int lane = t & 63;
    const int w = t >> 6;
    const int wr = w >> 1, wc = w & 1;

    __shared__ __align__(16) f16 As[64][40];
    __shared__ __align__(16) f16 Ks[64][40];

    f32x4 acc[2][2] = {};
    const int d = t >> 3;
    const int e8 = (t & 7) * 8;

    for (int kk = 0; kk < nkk; ++kk) {
        const float* gq = Wq + (size_t)(h * H + kk * 32 + d) * H + ecol + e8;
        const float* gk = Wk + (size_t)(h * H + kk * 32 + d) * H + frow + e8;
        float q[8], k[8];
#pragma unroll
        for (int i = 0; i < 8; ++i) { q[i] = gq[i]; k[i] = gk[i]; }
        __syncthreads();
#pragma unroll
        for (int i = 0; i < 8; ++i) { As[e8 + i][d] = (f16)q[i]; Ks[e8 + i][d] = (f16)k[i]; }
        __syncthreads();
        f16x8 a[2], b[2];
#pragma unroll
        for (int rt = 0; rt < 2; ++rt)
            a[rt] = *(const f16x8*)&Ks[wr * 32 + rt * 16 + (lane & 15)][(lane >> 4) * 8];
#pragma unroll
        for (int nt = 0; nt < 2; ++nt)
            b[nt] = *(const f16x8*)&As[wc * 32 + nt * 16 + (lane & 15)][(lane >> 4) * 8];
#pragma unroll
        for (int rt = 0; rt < 2; ++rt)
#pragma unroll
            for (int nt = 0; nt < 2; ++nt)
                acc[rt][nt] = MFMA16(a[rt], b[nt], acc[rt][nt]);
    }
#pragma unroll
    for (int rt = 0; rt < 2; ++rt)
#pragma unroll
        for (int nt = 0; nt < 2; ++nt)
#pragma unroll
            for (int j = 0; j < 4; ++j) {
                int f = frow + wr * 32 + rt * 16 + (lane >> 4) * 4 + j;
                int e = ecol + wc * 32 + nt * 16 + (lane & 15);
                MT[(((size_t)h * nkk + (e >> 5)) * H + f) * 32 + (e & 31)] = (f16)acc[rt][nt][j];
            }
}

// =====================================================================
// k_lin: out[r][j] = sum_d in[r][d]*W[j][d] + b[j], J=256, 4 rows/block.
// =====================================================================
__global__ __launch_bounds__(256) void k_lin(const float* __restrict__ in,
                                             const float* __restrict__ W,
                                             const float* __restrict__ bias,
                                             float* __restrict__ out, int K) {
    const int t = threadIdx.x;
    const int r0 = blockIdx.x * 4;
    __shared__ float ins[4][384];
    __shared__ float Ws[256][33];
#pragma unroll
    for (int r = 0; r < 4; ++r)
        for (int off = t; off < K; off += 256)
            ins[r][off] = in[(size_t)(r0 + r) * K + off];
    float acc[4] = {};
    for (int d0 = 0; d0 < K; d0 += 32) {
        __syncthreads();
        for (int i = t; i < 256 * 32; i += 256) {
            int j = i >> 5, dd = i & 31;
            Ws[j][dd] = W[(size_t)j * K + d0 + dd];
        }
        __syncthreads();
#pragma unroll 8
        for (int dd = 0; dd < 32; ++dd) {
            float wv = Ws[t][dd];
#pragma unroll
            for (int r = 0; r < 4; ++r) acc[r] += wv * ins[r][d0 + dd];
        }
    }
    float bv = bias[t];
#pragma unroll
    for (int r = 0; r < 4; ++r) out[(size_t)(r0 + r) * 256 + t] = acc[r] + bv;
}

// =====================================================================
// k_small_int: 4 pos-groups/block (16 X-rows) -> 1024 blocks, 4 blk/CU.
// grid (64, 16), block 256, static LDS ~17 KB.
// =====================================================================
__global__ __launch_bounds__(256) void k_small_int(const float* __restrict__ X,
                                                   const f16* __restrict__ MT,
                                                   float* __restrict__ wpart) {
    const int t = threadIdx.x;
    const int lane = t & 63;
    const int w = t >> 6;
    const int g = lane >> 4;
    const int l15 = lane & 15;
    const int pos0 = blockIdx.x * 4;
    const int h = blockIdx.y;

    __shared__ __align__(16) f16 Xs[16][264];
    __shared__ __align__(16) f16 Ts[16][264];

    {
        int row = t >> 4, d0 = (t & 15) * 16;
        int s = row & 3, p = row >> 2;
        const float* gx = X + (size_t)(s * 256 + pos0 + p) * 256 + d0;
#pragma unroll
        for (int i = 0; i < 16; i += 8) {
            float4 v0 = *(const float4*)(gx + i);
            float4 v1 = *(const float4*)(gx + i + 4);
            f16x8 o;
            o[0] = (f16)v0.x; o[1] = (f16)v0.y; o[2] = (f16)v0.z; o[3] = (f16)v0.w;
            o[4] = (f16)v1.x; o[5] = (f16)v1.y; o[6] = (f16)v1.z; o[7] = (f16)v1.w;
            *(f16x8*)&Xs[row][d0 + i] = o;
        }
    }
    __syncthreads();

    const f16* mh = MT + (size_t)h * 8 * 256 * 32;
    const int fb = w * 64 + l15;
    f32x4 acc[4] = {};
    f16x8 bq[4], bn[4];
#pragma unroll
    for (int nt = 0; nt < 4; ++nt)
        bq[nt] = *(const f16x8*)(mh + (size_t)(fb + nt * 16) * 32 + g * 8);
#pragma unroll
    for (int kk = 0; kk < 8; ++kk) {
        if (kk < 7) {
#pragma unroll
            for (int nt = 0; nt < 4; ++nt)
                bn[nt] = *(const f16x8*)(mh + ((size_t)(kk + 1) * 256 + fb + nt * 16) * 32 + g * 8);
        }
        f16x8 a = *(const f16x8*)&Xs[l15][kk * 32 + g * 8];
#pragma unroll
        for (int nt = 0; nt < 4; ++nt) acc[nt] = MFMA16(a, bq[nt], acc[nt]);
#pragma unroll
        for (int nt = 0; nt < 4; ++nt) bq[nt] = bn[nt];
    }
#pragma unroll
    for (int nt = 0; nt < 4; ++nt)
#pragma unroll
        for (int j = 0; j < 4; ++j)
            Ts[g * 4 + j][w * 64 + nt * 16 + l15] = (f16)acc[nt][j];
    __syncthreads();

    f32x4 sacc = {};
#pragma unroll
    for (int ks = 0; ks < 8; ++ks) {
        f16x8 a = *(const f16x8*)&Ts[l15][ks * 32 + g * 8];
        f16x8 b = *(const f16x8*)&Xs[l15][ks * 32 + g * 8];
        sacc = MFMA16(a, b, sacc);
    }
    if (w == 0 && (l15 >> 2) == g) {
        const float scale = 1.0f / 16.0f; // 1/sqrt(256)
        float add = 0.f;
#pragma unroll
        for (int j = 0; j < 4; ++j) {
            float v = sacc[j] * scale;
            float m = v;
            m = fmaxf(m, __shfl_xor(m, 1));
            m = fmaxf(m, __shfl_xor(m, 2));
            float e = expf(v - m);
            float s2 = e;
            s2 += __shfl_xor(s2, 1);
            s2 += __shfl_xor(s2, 2);
            add += e / s2;
        }
        int pg = pos0 + g;
        wpart[((size_t)h * 256 + pg) * 4 + (l15 & 3)] = add;
    }
}

// =====================================================================
// k_small_fin: sum 16 head-partials -> /64 -> softmax(4) -> pool states.
// =====================================================================
__global__ __launch_bounds__(256) void k_small_fin(const float* __restrict__ wpart,
                                                   const float* __restrict__ X,
                                                   float* __restrict__ out_int,
                                                   float* __restrict__ out_w) {
    const int pos = blockIdx.x, t = threadIdx.x;
    __shared__ float red[64];
    __shared__ float ws[4];
    if (t < 64) red[t] = wpart[((size_t)(t >> 2) * 256 + pos) * 4 + (t & 3)];
    __syncthreads();
    if (t == 0) {
        float v[4];
#pragma unroll
        for (int s = 0; s < 4; ++s) {
            float x = 0.f;
            for (int hh = 0; hh < 16; ++hh) x += red[hh * 4 + s];
            v[s] = x * (1.0f / 64.0f);
        }
        float m = fmaxf(fmaxf(v[0], v[1]), fmaxf(v[2], v[3]));
        float sum = 0.f;
#pragma unroll
        for (int s = 0; s < 4; ++s) { v[s] = expf(v[s] - m); sum += v[s]; }
#pragma unroll
        for (int s = 0; s < 4; ++s) ws[s] = v[s] / sum;
    }
    __syncthreads();
    if (t < 4) out_w[pos * 4 + t] = ws[t];
    float v = 0.f;
#pragma unroll
    for (int s = 0; s < 4; ++s) v += ws[s] * X[(size_t)(s * 256 + pos) * 256 + t];
    out_int[(size_t)pos * 256 + t] = v;
}

// =====================================================================
// k_ce_int v8: 128 tokens (4 b's)/block, 8 waves x 48 e'-cols, grid 256.
// Halves per-CU M L2 traffic vs v6 (M streamed once per 128 tokens).
// Tt = M^T X (lane=token); phase2 B-frag == acc layout (K16 MFMA).
// Merge: 2 rounds (2 b's each): all waves publish 8 slices (64KB BUF),
// owner wave (b*2+it) sums 8 srcs; softmax+colsum fully intra-wave.
// LDS: X 98304 (128x768B swz) + BUF 65536 = 163840. 1 blk/CU, 8 waves.
// acc_out: [16][1024][2][32]. grid 256, block 512.
// =====================================================================
#define BUF_OFF 98304

__global__ __launch_bounds__(512, 2) void k_ce_int(const float* __restrict__ Xg32,
                                                   const f16* __restrict__ MT,
                                                   float* __restrict__ acc_out) {
    const int t = threadIdx.x;
    const int lane = t & 63;
    const int w = t >> 6;       // 0..7
    const int g = lane >> 4;
    const int l15 = lane & 15;
    const int bg = blockIdx.x;  // 0..255, 4 b's each

    extern __shared__ __align__(16) char smem[];
    char* BUF = smem + BUF_OFF;

    // ---- stage X (128 x 384), f32 -> f16, source-swizzled, linear LDS ----
    {
        const float* xg = Xg32 + (size_t)bg * 128 * 384;
#pragma unroll
        for (int p = 0; p < 12; ++p) {
            int idx = p * 512 + t;          // 6144 16B units
            int row = idx / 48, s = idx - row * 48;
            int c = s ^ (row & 7);
            const float* src = xg + row * 384 + c * 8;
            float4 v0 = *(const float4*)src;
            float4 v1 = *(const float4*)(src + 4);
            f16x8 o;
            o[0] = (f16)v0.x; o[1] = (f16)v0.y; o[2] = (f16)v0.z; o[3] = (f16)v0.w;
            o[4] = (f16)v1.x; o[5] = (f16)v1.y; o[6] = (f16)v1.z; o[7] = (f16)v1.w;
            *(f16x8*)(smem + idx * 16) = o;
        }
    }
    __syncthreads();

    const f16* mall = MT;            // [192 steps][384][32]
    const int frow = w * 48 + l15;

    // depth-2 M prefetch: 3 buffers, A[step%3]
    f16x8 A[3][3];
#pragma unroll
    for (int ft = 0; ft < 3; ++ft) {
        A[0][ft] = *(const f16x8*)(mall + (size_t)(frow + ft * 16) * 32 + g * 8);
        A[1][ft] = *(const f16x8*)(mall + (size_t)12288 + (size_t)(frow + ft * 16) * 32 + g * 8);
    }

    for (int hi = 0; hi < 16; ++hi) {
        // ---- phase 1: Tt = M_h^T @ X; wave owns 48 e'-rows, 128 tokens ----
        f32x4 acc[3][8] = {};
#pragma unroll
        for (int kk = 0; kk < 12; ++kk) {
            {
                int step = hi * 12 + kk + 2;
                int ns = step < 192 ? step : 191;
#pragma unroll
                for (int ft = 0; ft < 3; ++ft)
                    A[(kk + 2) % 3][ft] =
                        *(const f16x8*)(mall + (size_t)ns * 12288 + (size_t)(frow + ft * 16) * 32 + g * 8);
            }
            f16x8 xb[8];
#pragma unroll
            for (int mt = 0; mt < 8; ++mt) {
                int row = mt * 16 + l15;
                int ch = kk * 4 + g;
                xb[mt] = *(const f16x8*)(smem + row * 768 + ((ch ^ (row & 7)) << 4));
            }
            __builtin_amdgcn_s_setprio(1);
#pragma unroll
            for (int ft = 0; ft < 3; ++ft)
#pragma unroll
                for (int mt = 0; mt < 8; ++mt)
                    acc[ft][mt] = MFMA16(A[kk % 3][ft], xb[mt], acc[ft][mt]);
            __builtin_amdgcn_s_setprio(0);
        }

        // ---- cast Tt acc -> f16 B-frags (layout == K16 B-frag) ----
        f16x4 bf[3][8];
#pragma unroll
        for (int ft = 0; ft < 3; ++ft)
#pragma unroll
            for (int mt = 0; mt < 8; ++mt) {
                f32x4 v = acc[ft][mt];
                f16x4 o;
                o[0] = (f16)v[0]; o[1] = (f16)v[1]; o[2] = (f16)v[2]; o[3] = (f16)v[3];
                bf[ft][mt] = o;
            }

        // ---- phase 2 + merge: 2 rounds, 2 b's per round ----
#pragma unroll
        for (int r = 0; r < 2; ++r) {
            // S partials over this wave's 48 e' for b = 2r, 2r+1 (reg-only)
            f32x4 s2[2][2][2] = {};  // [bb][it][lt]
#pragma unroll
            for (int bb = 0; bb < 2; ++bb) {
                const int b = 2 * r + bb;
#pragma unroll
                for (int ks = 0; ks < 3; ++ks)
#pragma unroll
                    for (int it = 0; it < 2; ++it) {
                        int row = b * 32 + it * 16 + l15;
                        int ch = 6 * w + 2 * ks + (g >> 1);
                        f16x4 av = *(const f16x4*)(smem + row * 768 +
                                                   ((ch ^ (row & 7)) << 4) + 8 * (g & 1));
#pragma unroll
                        for (int lt = 0; lt < 2; ++lt)
                            s2[bb][it][lt] = MFMA16K16(av, bf[ks][2 * b + lt], s2[bb][it][lt]);
                    }
            }
            // publish all 8 slices: BUF[src w][slice][lane]
#pragma unroll
            for (int bb = 0; bb < 2; ++bb)
#pragma unroll
                for (int it = 0; it < 2; ++it)
#pragma unroll
                    for (int lt = 0; lt < 2; ++lt)
                        *(f32x4*)(BUF + w * 8192 + (bb * 4 + it * 2 + lt) * 1024 + lane * 16) =
                            s2[bb][it][lt];
            __syncthreads();

            // owners this round: waves with w>>2 == r; wl = w&3 -> (bb, it)
            if ((w >> 2) == r) {
                const int wl = w & 3;
                const int bb = wl >> 1;
                const int it = wl & 1;
                const int b = 2 * r + bb;
                f32x4 sum0 = {0.f, 0.f, 0.f, 0.f};
                f32x4 sum1 = {0.f, 0.f, 0.f, 0.f};
#pragma unroll
                for (int src = 0; src < 8; ++src) {
                    const char* pb = BUF + src * 8192 + (bb * 4 + it * 2) * 1024 + lane * 16;
                    sum0 += *(const f32x4*)pb;
                    sum1 += *(const f32x4*)(pb + 1024);
                }
                // softmax over m (32 = 2 regs x l15) per row (g*4+j), then colsum
                const float scale = 0.051031036307982884f; // 1/sqrt(384)
                float cs0 = 0.f, cs1 = 0.f;
#pragma unroll
                for (int j = 0; j < 4; ++j) {
                    float v0 = sum0[j] * scale, v1 = sum1[j] * scale;
                    float m = fmaxf(v0, v1);
                    m = fmaxf(m, __shfl_xor(m, 1));
                    m = fmaxf(m, __shfl_xor(m, 2));
                    m = fmaxf(m, __shfl_xor(m, 4));
                    m = fmaxf(m, __shfl_xor(m, 8));
                    float e0 = expf(v0 - m), e1 = expf(v1 - m);
                    float s = e0 + e1;
                    s += __shfl_xor(s, 1);
                    s += __shfl_xor(s, 2);
                    s += __shfl_xor(s, 4);
                    s += __shfl_xor(s, 8);
                    float inv = 1.f / s;
                    cs0 += e0 * inv;
                    cs1 += e1 * inv;
                }
                // sum over rows: j done above (accumulated), now over g
                cs0 += __shfl_xor(cs0, 16); cs0 += __shfl_xor(cs0, 32);
                cs1 += __shfl_xor(cs1, 16); cs1 += __shfl_xor(cs1, 32);
                if (lane < 16) {
                    float* o = acc_out + (((size_t)hi * 1024 + bg * 4 + b) * 2 + it) * 32;
                    o[l15] = cs0;
                    o[16 + l15] = cs1;
                }
            }
            __syncthreads();
        }
    }
}

// =====================================================================
// k_ce_pool: w = softmax(sum_{h,it} accp / 512); pooled = sum_m w[m]*exv
// accp: [16][1024][2][32]
// =====================================================================
__global__ __launch_bounds__(128) void k_ce_pool(const float* __restrict__ accp,
                                                 const float* __restrict__ exv,
                                                 float* __restrict__ pooled) {
    const int b = blockIdx.x;
    const int t = threadIdx.x;
    __shared__ float wm[32];
    __shared__ float ww[32];
    if (t < 32) {
        float s = 0.f;
#pragma unroll
        for (int h = 0; h < 16; ++h) {
            s += accp[(((size_t)h * 1024 + b) * 2 + 0) * 32 + t];
            s += accp[(((size_t)h * 1024 + b) * 2 + 1) * 32 + t];
        }
        wm[t] = s * (1.0f / 512.0f);
    }
    __syncthreads();
    if (t == 0) {
        float m = wm[0];
        for (int i = 1; i < 32; ++i) m = fmaxf(m, wm[i]);
        float s = 0.f;
        for (int i = 0; i < 32; ++i) { float e = expf(wm[i] - m); ww[i] = e; s += e; }
        float inv = 1.f / s;
        for (int i = 0; i < 32; ++i) ww[i] *= inv;
    }
    __syncthreads();
    for (int d = t; d < 384; d += 128) {
        float v = 0.f;
#pragma unroll
        for (int m = 0; m < 32; ++m) v += ww[m] * exv[((size_t)b * 32 + m) * 384 + d];
        pooled[(size_t)b * 384 + d] = v;
    }
}

// =====================================================================
extern "C" void kernel_launch(void* const* d_in, const int* in_sizes, int n_in,
                              void* d_out, int out_size, void* d_ws, size_t ws_size,
                              hipStream_t stream) {
    const float* h_V    = (const float*)d_in[0];
    const float* h_EXV  = (const float*)d_in[1];
    const float* W_hV   = (const float*)d_in[2];
    const float* b_hV   = (const float*)d_in[3];
    const float* Wq_hv  = (const float*)d_in[4];
    const float* Wk_hv  = (const float*)d_in[5];
    const float* Wq_ce  = (const float*)d_in[6];
    const float* Wk_ce  = (const float*)d_in[7];
    const float* W_ce   = (const float*)d_in[8];
    const float* b_ce   = (const float*)d_in[9];
    const float* Wq_sce = (const float*)d_in[10];
    const float* Wk_sce = (const float*)d_in[11];
    float* out = (float*)d_out;

    char* ws = (char*)d_ws;
    f16*   mt_hv  = (f16*)(ws + 0);           //  2,097,152
    f16*   mt_sce = (f16*)(ws + 2097152);     //  2,097,152
    f16*   mt_ce  = (f16*)(ws + 4194304);     //  4,718,592
    float* hv     = (float*)(ws + 8912896);   //  1,048,576
    float* ce     = (float*)(ws + 9961472);   //  1,048,576
    float* accp   = (float*)(ws + 11010048);  //  4,194,304
    float* pooled = (float*)(ws + 15204352);  //  1,572,864  (total ~16.8 MB)
    float* wpart  = accp;                     // alias: lifetimes ordered

    k_mt<<<dim3(16, 16), 256, 0, stream>>>(Wq_hv, Wk_hv, mt_hv, 256);
    k_mt<<<dim3(16, 36), 256, 0, stream>>>(Wq_ce, Wk_ce, mt_ce, 384);
    k_mt<<<dim3(16, 16), 256, 0, stream>>>(Wq_sce, Wk_sce, mt_sce, 256);
    k_lin<<<256, 256, 0, stream>>>(h_V, W_hV, b_hV, hv, 128);
    k_small_int<<<dim3(64, 16), 256, 0, stream>>>(hv, mt_hv, wpart);
    k_small_fin<<<256, 256, 0, stream>>>(wpart, hv, out + 0, out + 65536);
    k_ce_int<<<dim3(256), 512, 163840, stream>>>(h_EXV, mt_ce, accp);
    k_ce_pool<<<1024, 128, 0, stream>>>(accp, h_EXV, pooled);
    k_lin<<<256, 256, 0, stream>>>(pooled, W_ce, b_ce, ce, 384);
    k_small_int<<<dim3(64, 16), 256, 0, stream>>>(ce, mt_sce, wpart);
    k_small_fin<<<256, 256, 0, stream>>>(wpart, ce, out + 66560, out + 132096);
}